// Round 1
// baseline (167.362 us; speedup 1.0000x reference)
//
#include <hip/hip_runtime.h>
#include <stdint.h>

// HilbertSerialization: stable argsort of 26-bit Hilbert+batch keys.
// Structure: genkeys(+hist0) -> [scan,scan,scatter] x 3 passes of 9-bit LSD radix.
// Stability: in-block rank = wave ballot-match rank + cross-wave cnt matrix +
// per-block running counters; global offset = digitBase + per-block exclusive hist.

#define THREADS 256
#define TILE 2048            // elements per block (8 rounds of 256)
#define NBINS 512            // 9-bit digits
#define RADIX_BITS 9

// ---------------- Hilbert key (Skilling transpose algorithm, DEPTH=8) --------
__device__ __forceinline__ uint32_t hilbert_code(uint32_t x, uint32_t y, uint32_t z) {
  uint32_t X0 = x & 255u, X1 = y & 255u, X2 = z & 255u;
#pragma unroll
  for (int p = 7; p >= 0; --p) {
    uint32_t Q = 1u << p, low = Q - 1u;
    // dim 0: if bit set, flip low bits of X0 (swap with itself is a no-op)
    uint32_t f0 = (uint32_t)-(int)((X0 >> p) & 1u);
    X0 ^= (low & f0);
    // dim 1: bit set -> flip X0 low; else swap low bits of X0,X1
    uint32_t f1 = (uint32_t)-(int)((X1 >> p) & 1u);
    uint32_t t1 = ((X0 ^ X1) & low) & ~f1;
    X0 ^= (low & f1) ^ t1;
    X1 ^= t1;
    // dim 2
    uint32_t f2 = (uint32_t)-(int)((X2 >> p) & 1u);
    uint32_t t2 = ((X0 ^ X2) & low) & ~f2;
    X0 ^= (low & f2) ^ t2;
    X2 ^= t2;
  }
  // Interleave MSB-first: bit-plane k (k=0 is MSB), dims x,y,z; weight 23-(3k+dim)
  uint32_t G = 0;
#pragma unroll
  for (int k = 0; k < 8; ++k) {
    int p = 7 - k;
    G |= ((X0 >> p) & 1u) << (23 - 3 * k);
    G |= ((X1 >> p) & 1u) << (22 - 3 * k);
    G |= ((X2 >> p) & 1u) << (21 - 3 * k);
  }
  // gray -> binary: prefix XOR (order of shifts irrelevant: (1+x^s) products commute)
  G ^= G >> 16; G ^= G >> 8; G ^= G >> 4; G ^= G >> 2; G ^= G >> 1;
  return G & 0xFFFFFFu;
}

// ---------------- key generation fused with pass-0 histogram -----------------
__global__ __launch_bounds__(THREADS) void genkeys_hist(
    const int4* __restrict__ coords, const void* __restrict__ ss,
    const int* __restrict__ shifts, uint32_t* __restrict__ keys,
    int* __restrict__ vals, int* __restrict__ hist, int N, int nblocks) {
  __shared__ int lh[NBINS];
  int t = threadIdx.x, b = blockIdx.x;
  for (int d = t; d < NBINS; d += THREADS) lh[d] = 0;

  // sparse_shape may arrive as int64 ([32,0,512,0,512,0] as int32 view) or int32.
  const int* p32 = (const int*)ss;
  int D, H, W;
  if (p32[1] == 0) { const long long* p64 = (const long long*)ss;
    D = (int)p64[0]; H = (int)p64[1]; W = (int)p64[2]; }
  else { D = p32[0]; H = p32[1]; W = p32[2]; }
  int sflag = shifts[0];
  int sx = sflag ? 15 : 0, sy = sflag ? 15 : 0, sz = sflag ? 4 : 0;
  bool wp2 = (W & (W - 1)) == 0, hp2 = (H & (H - 1)) == 0, dp2 = (D & (D - 1)) == 0;
  __syncthreads();

#pragma unroll
  for (int r = 0; r < TILE / THREADS; ++r) {
    int idx = b * TILE + r * THREADS + t;
    if (idx < N) {
      int4 c = coords[idx];            // (b, z, y, x)
      uint32_t bb = (uint32_t)c.x;
      int zz = c.y + sz, yy = c.z + sy, xx = c.w + sx;
      uint32_t z = (uint32_t)(dp2 ? (zz & (D - 1)) : (zz % D));
      uint32_t y = (uint32_t)(hp2 ? (yy & (H - 1)) : (yy % H));
      uint32_t x = (uint32_t)(wp2 ? (xx & (W - 1)) : (xx % W));
      uint32_t code = hilbert_code(x, y, z) | (bb << 24);
      keys[idx] = code;
      vals[idx] = idx;
      atomicAdd(&lh[code & (NBINS - 1)], 1);
    }
  }
  __syncthreads();
  for (int d = t; d < NBINS; d += THREADS) hist[d * nblocks + b] = lh[d];
}

// ---------------- per-pass histogram ----------------
template <int SHIFT>
__global__ __launch_bounds__(THREADS) void hist_kernel(
    const uint32_t* __restrict__ keys, int* __restrict__ hist, int N, int nblocks) {
  __shared__ int lh[NBINS];
  int t = threadIdx.x, b = blockIdx.x;
  for (int d = t; d < NBINS; d += THREADS) lh[d] = 0;
  __syncthreads();
#pragma unroll
  for (int r = 0; r < TILE / THREADS; ++r) {
    int idx = b * TILE + r * THREADS + t;
    if (idx < N) atomicAdd(&lh[(keys[idx] >> SHIFT) & (NBINS - 1)], 1);
  }
  __syncthreads();
  for (int d = t; d < NBINS; d += THREADS) hist[d * nblocks + b] = lh[d];
}

// ---- scan 1: per digit, exclusive scan over blocks (in place), total out ----
__global__ __launch_bounds__(THREADS) void scan_blocks(
    int* __restrict__ hist, int* __restrict__ digitTotals, int nblocks) {
  __shared__ int s[512];
  int d = blockIdx.x, t = threadIdx.x;
  long long base = (long long)d * nblocks;
  int carry = 0;
  for (int start = 0; start < nblocks; start += 512) {
    int i0 = start + t, i1 = start + t + 256;
    int v0 = (i0 < nblocks) ? hist[base + i0] : 0;
    int v1 = (i1 < nblocks) ? hist[base + i1] : 0;
    s[t] = v0; s[t + 256] = v1;
    __syncthreads();
    for (int off = 1; off < 512; off <<= 1) {
      int a0 = (t >= off) ? s[t - off] : 0;
      int a1 = (t + 256 >= off) ? s[t + 256 - off] : 0;
      int b0 = s[t], b1 = s[t + 256];
      __syncthreads();
      s[t] = b0 + a0; s[t + 256] = b1 + a1;
      __syncthreads();
    }
    if (i0 < nblocks) hist[base + i0] = carry + s[t] - v0;
    if (i1 < nblocks) hist[base + i1] = carry + s[t + 256] - v1;
    int total = s[511];
    __syncthreads();
    carry += total;
  }
  if (t == 0) digitTotals[d] = carry;
}

// ---- scan 2: exclusive scan over the 512 digit totals ----
__global__ __launch_bounds__(THREADS) void scan_digits(
    const int* __restrict__ totals, int* __restrict__ digitBase) {
  __shared__ int s[512];
  int t = threadIdx.x;
  int v0 = totals[t], v1 = totals[t + 256];
  s[t] = v0; s[t + 256] = v1;
  __syncthreads();
  for (int off = 1; off < 512; off <<= 1) {
    int a0 = (t >= off) ? s[t - off] : 0;
    int a1 = (t + 256 >= off) ? s[t + 256 - off] : 0;
    int b0 = s[t], b1 = s[t + 256];
    __syncthreads();
    s[t] = b0 + a0; s[t + 256] = b1 + a1;
    __syncthreads();
  }
  digitBase[t] = s[t] - v0;
  digitBase[t + 256] = s[t + 256] - v1;
}

// ---------------- stable scatter ----------------
template <int SHIFT, bool WRITE_KEYS>
__global__ __launch_bounds__(THREADS) void scatter_kernel(
    const uint32_t* __restrict__ keysIn, const int* __restrict__ valsIn,
    uint32_t* __restrict__ keysOut, int* __restrict__ valsOut,
    const int* __restrict__ hist, const int* __restrict__ digitBase,
    int N, int nblocks) {
  __shared__ int baseArr[NBINS];
  __shared__ int runCount[NBINS];
  __shared__ int cnt[4][NBINS];
  int t = threadIdx.x, b = blockIdx.x;
  for (int d = t; d < NBINS; d += THREADS) {
    baseArr[d] = digitBase[d] + hist[d * nblocks + b];
    runCount[d] = 0;
    cnt[0][d] = 0; cnt[1][d] = 0; cnt[2][d] = 0; cnt[3][d] = 0;
  }
  __syncthreads();
  int wave = t >> 6, lane = t & 63;
  uint64_t lt = (1ull << lane) - 1ull;
#pragma unroll
  for (int r = 0; r < TILE / THREADS; ++r) {
    int idx = b * TILE + r * THREADS + t;
    bool valid = idx < N;
    uint32_t key = 0; int val = 0;
    if (valid) { key = keysIn[idx]; val = valsIn[idx]; }
    int digit = (int)((key >> SHIFT) & (NBINS - 1));
    uint64_t vm = __ballot(valid);
    uint64_t eq = vm;
#pragma unroll
    for (int bit = 0; bit < RADIX_BITS; ++bit) {
      uint64_t m = __ballot((digit >> bit) & 1);
      eq &= ((digit >> bit) & 1) ? m : ~m;
    }
    int waveRank = __popcll(eq & lt);
    int cntW = __popcll(eq);
    bool leader = valid && (waveRank == 0);
    if (leader) cnt[wave][digit] = cntW;
    __syncthreads();
    if (valid) {
      int prefix = 0;
      for (int w = 0; w < wave; ++w) prefix += cnt[w][digit];
      int pos = baseArr[digit] + runCount[digit] + prefix + waveRank;
      if (WRITE_KEYS) keysOut[pos] = key;
      valsOut[pos] = val;
    }
    __syncthreads();
    if (leader) { atomicAdd(&runCount[digit], cntW); cnt[wave][digit] = 0; }
    __syncthreads();
  }
}

// ---------------- launch ----------------
extern "C" void kernel_launch(void* const* d_in, const int* in_sizes, int n_in,
                              void* d_out, int out_size, void* d_ws, size_t ws_size,
                              hipStream_t stream) {
  const int4* coords = (const int4*)d_in[0];
  const void* ss = d_in[1];
  const int* shifts = (const int*)d_in[2];
  int N = in_sizes[0] / 4;
  int nblocks = (N + TILE - 1) / TILE;

  char* ws = (char*)d_ws;
  size_t off = 0;
  auto alloc = [&](size_t bytes) -> void* {
    void* p = ws + off;
    off += (bytes + 255) & ~(size_t)255;
    return p;
  };
  uint32_t* keysA = (uint32_t*)alloc((size_t)N * 4);
  int*      valsA = (int*)alloc((size_t)N * 4);
  uint32_t* keysB = (uint32_t*)alloc((size_t)N * 4);
  int*      valsB = (int*)alloc((size_t)N * 4);
  int*      hist  = (int*)alloc((size_t)NBINS * nblocks * 4);
  int*      digitTotals = (int*)alloc(NBINS * 4);
  int*      digitBase   = (int*)alloc(NBINS * 4);

  // pass 0 (bits 0..8): genkeys fused with histogram
  genkeys_hist<<<nblocks, THREADS, 0, stream>>>(coords, ss, shifts, keysA, valsA, hist, N, nblocks);
  scan_blocks<<<NBINS, THREADS, 0, stream>>>(hist, digitTotals, nblocks);
  scan_digits<<<1, THREADS, 0, stream>>>(digitTotals, digitBase);
  scatter_kernel<0, true><<<nblocks, THREADS, 0, stream>>>(keysA, valsA, keysB, valsB, hist, digitBase, N, nblocks);

  // pass 1 (bits 9..17)
  hist_kernel<9><<<nblocks, THREADS, 0, stream>>>(keysB, hist, N, nblocks);
  scan_blocks<<<NBINS, THREADS, 0, stream>>>(hist, digitTotals, nblocks);
  scan_digits<<<1, THREADS, 0, stream>>>(digitTotals, digitBase);
  scatter_kernel<9, true><<<nblocks, THREADS, 0, stream>>>(keysB, valsB, keysA, valsA, hist, digitBase, N, nblocks);

  // pass 2 (bits 18..26): values land directly in d_out (int32 argsort indices)
  hist_kernel<18><<<nblocks, THREADS, 0, stream>>>(keysA, hist, N, nblocks);
  scan_blocks<<<NBINS, THREADS, 0, stream>>>(hist, digitTotals, nblocks);
  scan_digits<<<1, THREADS, 0, stream>>>(digitTotals, digitBase);
  scatter_kernel<18, false><<<nblocks, THREADS, 0, stream>>>(keysA, valsA, keysB, (int*)d_out, hist, digitBase, N, nblocks);
}

// Round 2
// 125.593 us; speedup vs baseline: 1.3326x; 1.3326x over previous
//
#include <hip/hip_runtime.h>
#include <stdint.h>

// HilbertSerialization: stable argsort of 26-bit Hilbert+batch keys.
// genkeys(+hist0) -> [scan,scan,scatter] x 3 passes of 9-bit LSD radix.
// Scatter v2: wave-private ranking (no barriers in rank loop, wave-major
// stability order) + LDS staging so global writes are digit-contiguous.

#define THREADS 256
#define TILE 2048            // elements per block
#define NBINS 512            // 9-bit digits
#define RADIX_BITS 9
#define ROUNDS (TILE / THREADS)   // 8
#define CHUNK (TILE / 4)          // 512 elements per wave

// ---------------- Hilbert key (Skilling transpose algorithm, DEPTH=8) --------
__device__ __forceinline__ uint32_t hilbert_code(uint32_t x, uint32_t y, uint32_t z) {
  uint32_t X0 = x & 255u, X1 = y & 255u, X2 = z & 255u;
#pragma unroll
  for (int p = 7; p >= 0; --p) {
    uint32_t low = (1u << p) - 1u;
    uint32_t f0 = (uint32_t)-(int)((X0 >> p) & 1u);
    X0 ^= (low & f0);
    uint32_t f1 = (uint32_t)-(int)((X1 >> p) & 1u);
    uint32_t t1 = ((X0 ^ X1) & low) & ~f1;
    X0 ^= (low & f1) ^ t1;
    X1 ^= t1;
    uint32_t f2 = (uint32_t)-(int)((X2 >> p) & 1u);
    uint32_t t2 = ((X0 ^ X2) & low) & ~f2;
    X0 ^= (low & f2) ^ t2;
    X2 ^= t2;
  }
  uint32_t G = 0;
#pragma unroll
  for (int k = 0; k < 8; ++k) {
    int p = 7 - k;
    G |= ((X0 >> p) & 1u) << (23 - 3 * k);
    G |= ((X1 >> p) & 1u) << (22 - 3 * k);
    G |= ((X2 >> p) & 1u) << (21 - 3 * k);
  }
  G ^= G >> 16; G ^= G >> 8; G ^= G >> 4; G ^= G >> 2; G ^= G >> 1;
  return G & 0xFFFFFFu;
}

// ---------------- key generation fused with pass-0 histogram -----------------
__global__ __launch_bounds__(THREADS) void genkeys_hist(
    const int4* __restrict__ coords, const void* __restrict__ ss,
    const int* __restrict__ shifts, uint32_t* __restrict__ keys,
    int* __restrict__ hist, int N, int nblocks) {
  __shared__ int lh[NBINS];
  int t = threadIdx.x, b = blockIdx.x;
  for (int d = t; d < NBINS; d += THREADS) lh[d] = 0;

  const int* p32 = (const int*)ss;
  int D, H, W;
  if (p32[1] == 0) { const long long* p64 = (const long long*)ss;
    D = (int)p64[0]; H = (int)p64[1]; W = (int)p64[2]; }
  else { D = p32[0]; H = p32[1]; W = p32[2]; }
  int sflag = shifts[0];
  int sx = sflag ? 15 : 0, sy = sflag ? 15 : 0, sz = sflag ? 4 : 0;
  bool wp2 = (W & (W - 1)) == 0, hp2 = (H & (H - 1)) == 0, dp2 = (D & (D - 1)) == 0;
  __syncthreads();

#pragma unroll
  for (int r = 0; r < ROUNDS; ++r) {
    int idx = b * TILE + r * THREADS + t;
    if (idx < N) {
      int4 c = coords[idx];            // (b, z, y, x)
      uint32_t bb = (uint32_t)c.x;
      int zz = c.y + sz, yy = c.z + sy, xx = c.w + sx;
      uint32_t z = (uint32_t)(dp2 ? (zz & (D - 1)) : (zz % D));
      uint32_t y = (uint32_t)(hp2 ? (yy & (H - 1)) : (yy % H));
      uint32_t x = (uint32_t)(wp2 ? (xx & (W - 1)) : (xx % W));
      uint32_t code = hilbert_code(x, y, z) | (bb << 24);
      keys[idx] = code;
      atomicAdd(&lh[code & (NBINS - 1)], 1);
    }
  }
  __syncthreads();
  for (int d = t; d < NBINS; d += THREADS) hist[d * nblocks + b] = lh[d];
}

// ---------------- per-pass histogram ----------------
template <int SHIFT>
__global__ __launch_bounds__(THREADS) void hist_kernel(
    const uint32_t* __restrict__ keys, int* __restrict__ hist, int N, int nblocks) {
  __shared__ int lh[NBINS];
  int t = threadIdx.x, b = blockIdx.x;
  for (int d = t; d < NBINS; d += THREADS) lh[d] = 0;
  __syncthreads();
#pragma unroll
  for (int r = 0; r < ROUNDS; ++r) {
    int idx = b * TILE + r * THREADS + t;
    if (idx < N) atomicAdd(&lh[(keys[idx] >> SHIFT) & (NBINS - 1)], 1);
  }
  __syncthreads();
  for (int d = t; d < NBINS; d += THREADS) hist[d * nblocks + b] = lh[d];
}

// ---- scan 1: per digit, exclusive scan over blocks (in place), total out ----
__global__ __launch_bounds__(THREADS) void scan_blocks(
    int* __restrict__ hist, int* __restrict__ digitTotals, int nblocks) {
  __shared__ int s[512];
  int d = blockIdx.x, t = threadIdx.x;
  long long base = (long long)d * nblocks;
  int carry = 0;
  for (int start = 0; start < nblocks; start += 512) {
    int i0 = start + t, i1 = start + t + 256;
    int v0 = (i0 < nblocks) ? hist[base + i0] : 0;
    int v1 = (i1 < nblocks) ? hist[base + i1] : 0;
    s[t] = v0; s[t + 256] = v1;
    __syncthreads();
    for (int off = 1; off < 512; off <<= 1) {
      int a0 = (t >= off) ? s[t - off] : 0;
      int a1 = (t + 256 >= off) ? s[t + 256 - off] : 0;
      int b0 = s[t], b1 = s[t + 256];
      __syncthreads();
      s[t] = b0 + a0; s[t + 256] = b1 + a1;
      __syncthreads();
    }
    if (i0 < nblocks) hist[base + i0] = carry + s[t] - v0;
    if (i1 < nblocks) hist[base + i1] = carry + s[t + 256] - v1;
    int total = s[511];
    __syncthreads();
    carry += total;
  }
  if (t == 0) digitTotals[d] = carry;
}

// ---- scan 2: exclusive scan over the 512 digit totals ----
__global__ __launch_bounds__(THREADS) void scan_digits(
    const int* __restrict__ totals, int* __restrict__ digitBase) {
  __shared__ int s[512];
  int t = threadIdx.x;
  int v0 = totals[t], v1 = totals[t + 256];
  s[t] = v0; s[t + 256] = v1;
  __syncthreads();
  for (int off = 1; off < 512; off <<= 1) {
    int a0 = (t >= off) ? s[t - off] : 0;
    int a1 = (t + 256 >= off) ? s[t + 256 - off] : 0;
    int b0 = s[t], b1 = s[t + 256];
    __syncthreads();
    s[t] = b0 + a0; s[t + 256] = b1 + a1;
    __syncthreads();
  }
  digitBase[t] = s[t] - v0;
  digitBase[t + 256] = s[t + 256] - v1;
}

// ---------------- stable scatter with LDS staging ----------------
// Stability order within block: (wave, round, lane) == original index order,
// since wave w owns the contiguous chunk [b*TILE + w*CHUNK, +CHUNK).
template <int SHIFT, bool WRITE_KEYS, bool VALS_FROM_INDEX>
__global__ __launch_bounds__(THREADS) void scatter_kernel(
    const uint32_t* __restrict__ keysIn, const int* __restrict__ valsIn,
    uint32_t* __restrict__ keysOut, int* __restrict__ valsOut,
    const int* __restrict__ hist, const int* __restrict__ digitBase,
    int N, int nblocks) {
  __shared__ uint32_t sbuf[TILE];                  // staging / scan scratch
  __shared__ unsigned short cnt[4][NBINS];         // per-wave digit counters -> offsets
  __shared__ int adjArr[NBINS];                    // digitBase+hist  ->  (that - digitStart)
  __shared__ int digitStart[NBINS];
  int t = threadIdx.x, b = blockIdx.x;
  int wave = t >> 6, lane = t & 63;

  for (int d = t; d < NBINS; d += THREADS) {
    adjArr[d] = digitBase[d] + hist[d * nblocks + b];
    cnt[0][d] = 0; cnt[1][d] = 0; cnt[2][d] = 0; cnt[3][d] = 0;
  }
  __syncthreads();

  uint32_t keyR[ROUNDS];
  int valR[ROUNDS];
  int drR[ROUNDS];                                 // digit | rankInChunk<<9, -1 invalid
  uint64_t lt = (1ull << lane) - 1ull;
  int chunk0 = b * TILE + wave * CHUNK;

  // ---- phase A: wave-private stable ranking (no barriers) ----
#pragma unroll
  for (int r = 0; r < ROUNDS; ++r) {
    int idx = chunk0 + r * 64 + lane;
    bool valid = idx < N;
    uint32_t key = valid ? keysIn[idx] : 0u;
    keyR[r] = key;
    valR[r] = VALS_FROM_INDEX ? idx : (valid ? valsIn[idx] : 0);
    int digit = (int)((key >> SHIFT) & (NBINS - 1));
    uint64_t eq = __ballot(valid);
#pragma unroll
    for (int bit = 0; bit < RADIX_BITS; ++bit) {
      uint64_t m = __ballot((digit >> bit) & 1);
      eq &= ((digit >> bit) & 1) ? m : ~m;
    }
    int waveRank = __popcll(eq & lt);
    int cntW = __popcll(eq);
    int prior = cnt[wave][digit];                  // wave-private row: no race
    drR[r] = valid ? (digit | ((prior + waveRank) << RADIX_BITS)) : -1;
    if (valid && waveRank == 0) cnt[wave][digit] = (unsigned short)(prior + cntW);
  }
  __syncthreads();

  // ---- cross-wave exclusive offsets per digit; totals into sbuf scratch ----
  for (int d = t; d < NBINS; d += THREADS) {
    int c0 = cnt[0][d], c1 = cnt[1][d], c2 = cnt[2][d], c3 = cnt[3][d];
    cnt[0][d] = 0;
    cnt[1][d] = (unsigned short)c0;
    cnt[2][d] = (unsigned short)(c0 + c1);
    cnt[3][d] = (unsigned short)(c0 + c1 + c2);
    ((int*)sbuf)[d] = c0 + c1 + c2 + c3;
  }
  __syncthreads();

  // ---- block-level exclusive scan of digit totals (scratch = sbuf) ----
  {
    int* s = (int*)sbuf;
    int v0 = s[t], v1 = s[t + 256];
    __syncthreads();
    for (int off = 1; off < 512; off <<= 1) {
      int a0 = (t >= off) ? s[t - off] : 0;
      int a1 = (t + 256 >= off) ? s[t + 256 - off] : 0;
      int b0 = s[t], b1 = s[t + 256];
      __syncthreads();
      s[t] = b0 + a0; s[t + 256] = b1 + a1;
      __syncthreads();
    }
    int e0 = s[t] - v0, e1 = s[t + 256] - v1;
    digitStart[t] = e0;
    digitStart[t + 256] = e1;
    adjArr[t] -= e0;                               // adj = globalBase - digitStart
    adjArr[t + 256] -= e1;
  }
  __syncthreads();

  // ---- stage keys into LDS in digit-sorted order ----
  int slotR[ROUNDS];
#pragma unroll
  for (int r = 0; r < ROUNDS; ++r) {
    int dr = drR[r];
    int slot = -1;
    if (dr >= 0) {
      int digit = dr & (NBINS - 1);
      int rnk = dr >> RADIX_BITS;
      slot = digitStart[digit] + (int)cnt[wave][digit] + rnk;
      sbuf[slot] = keyR[r];
    }
    slotR[r] = slot;
  }
  __syncthreads();

  // ---- write keys out sequentially (digit-contiguous), remember positions ----
  int validCount = min(TILE, N - b * TILE);
  int posR[ROUNDS];
#pragma unroll
  for (int j = 0; j < ROUNDS; ++j) {
    int i = j * THREADS + t;
    int pos = -1;
    if (i < validCount) {
      uint32_t k = sbuf[i];
      int digit = (int)((k >> SHIFT) & (NBINS - 1));
      pos = adjArr[digit] + i;
      if (WRITE_KEYS) keysOut[pos] = k;
    }
    posR[j] = pos;
  }
  __syncthreads();

  // ---- stage vals, write vals out ----
#pragma unroll
  for (int r = 0; r < ROUNDS; ++r)
    if (slotR[r] >= 0) sbuf[slotR[r]] = (uint32_t)valR[r];
  __syncthreads();
#pragma unroll
  for (int j = 0; j < ROUNDS; ++j)
    if (posR[j] >= 0) valsOut[posR[j]] = (int)sbuf[j * THREADS + t];
}

// ---------------- launch ----------------
extern "C" void kernel_launch(void* const* d_in, const int* in_sizes, int n_in,
                              void* d_out, int out_size, void* d_ws, size_t ws_size,
                              hipStream_t stream) {
  const int4* coords = (const int4*)d_in[0];
  const void* ss = d_in[1];
  const int* shifts = (const int*)d_in[2];
  int N = in_sizes[0] / 4;
  int nblocks = (N + TILE - 1) / TILE;

  char* ws = (char*)d_ws;
  size_t off = 0;
  auto alloc = [&](size_t bytes) -> void* {
    void* p = ws + off;
    off += (bytes + 255) & ~(size_t)255;
    return p;
  };
  uint32_t* keysA = (uint32_t*)alloc((size_t)N * 4);
  int*      valsA = (int*)alloc((size_t)N * 4);
  uint32_t* keysB = (uint32_t*)alloc((size_t)N * 4);
  int*      valsB = (int*)alloc((size_t)N * 4);
  int*      hist  = (int*)alloc((size_t)NBINS * nblocks * 4);
  int*      digitTotals = (int*)alloc(NBINS * 4);
  int*      digitBase   = (int*)alloc(NBINS * 4);

  // pass 0 (bits 0..8): vals are implicit (val == idx)
  genkeys_hist<<<nblocks, THREADS, 0, stream>>>(coords, ss, shifts, keysA, hist, N, nblocks);
  scan_blocks<<<NBINS, THREADS, 0, stream>>>(hist, digitTotals, nblocks);
  scan_digits<<<1, THREADS, 0, stream>>>(digitTotals, digitBase);
  scatter_kernel<0, true, true><<<nblocks, THREADS, 0, stream>>>(
      keysA, valsA, keysB, valsB, hist, digitBase, N, nblocks);

  // pass 1 (bits 9..17)
  hist_kernel<9><<<nblocks, THREADS, 0, stream>>>(keysB, hist, N, nblocks);
  scan_blocks<<<NBINS, THREADS, 0, stream>>>(hist, digitTotals, nblocks);
  scan_digits<<<1, THREADS, 0, stream>>>(digitTotals, digitBase);
  scatter_kernel<9, true, false><<<nblocks, THREADS, 0, stream>>>(
      keysB, valsB, keysA, valsA, hist, digitBase, N, nblocks);

  // pass 2 (bits 18..26): values land directly in d_out
  hist_kernel<18><<<nblocks, THREADS, 0, stream>>>(keysA, hist, N, nblocks);
  scan_blocks<<<NBINS, THREADS, 0, stream>>>(hist, digitTotals, nblocks);
  scan_digits<<<1, THREADS, 0, stream>>>(digitTotals, digitBase);
  scatter_kernel<18, false, false><<<nblocks, THREADS, 0, stream>>>(
      keysA, valsA, keysB, (int*)d_out, hist, digitBase, N, nblocks);
}

// Round 3
// 107.011 us; speedup vs baseline: 1.5640x; 1.1736x over previous
//
#include <hip/hip_runtime.h>
#include <stdint.h>

// HilbertSerialization: stable argsort of 26-bit Hilbert+batch keys.
// 3 passes x 9-bit LSD radix over fused (val<<32|key) uint64 pairs.
// genkeys(+hist0) -> [scan_blocks, scatter] x 3; digitBase scan fused
// into scatter (int2 LDS scan). Scatter stages pairs into LDS in
// digit-sorted order so global writes are 64B-run contiguous.

#define THREADS 256
#define TILE 4096                 // elements per block
#define NBINS 512                 // 9-bit digits
#define RADIX_BITS 9
#define ROUNDS (TILE / THREADS)   // 16
#define CHUNK (TILE / 4)          // 1024 elements per wave

// ---------------- Hilbert key (Skilling transpose algorithm, DEPTH=8) --------
__device__ __forceinline__ uint32_t hilbert_code(uint32_t x, uint32_t y, uint32_t z) {
  uint32_t X0 = x & 255u, X1 = y & 255u, X2 = z & 255u;
#pragma unroll
  for (int p = 7; p >= 0; --p) {
    uint32_t low = (1u << p) - 1u;
    uint32_t f0 = (uint32_t)-(int)((X0 >> p) & 1u);
    X0 ^= (low & f0);
    uint32_t f1 = (uint32_t)-(int)((X1 >> p) & 1u);
    uint32_t t1 = ((X0 ^ X1) & low) & ~f1;
    X0 ^= (low & f1) ^ t1;
    X1 ^= t1;
    uint32_t f2 = (uint32_t)-(int)((X2 >> p) & 1u);
    uint32_t t2 = ((X0 ^ X2) & low) & ~f2;
    X0 ^= (low & f2) ^ t2;
    X2 ^= t2;
  }
  uint32_t G = 0;
#pragma unroll
  for (int k = 0; k < 8; ++k) {
    int p = 7 - k;
    G |= ((X0 >> p) & 1u) << (23 - 3 * k);
    G |= ((X1 >> p) & 1u) << (22 - 3 * k);
    G |= ((X2 >> p) & 1u) << (21 - 3 * k);
  }
  G ^= G >> 16; G ^= G >> 8; G ^= G >> 4; G ^= G >> 2; G ^= G >> 1;
  return G & 0xFFFFFFu;
}

// ---------------- key generation fused with pass-0 histogram -----------------
__global__ __launch_bounds__(THREADS) void genkeys_hist(
    const int4* __restrict__ coords, const void* __restrict__ ss,
    const int* __restrict__ shifts, uint64_t* __restrict__ pairs,
    int* __restrict__ hist, int N, int nblocks) {
  __shared__ int lh[NBINS];
  int t = threadIdx.x, b = blockIdx.x;
  for (int d = t; d < NBINS; d += THREADS) lh[d] = 0;

  const int* p32 = (const int*)ss;
  int D, H, W;
  if (p32[1] == 0) { const long long* p64 = (const long long*)ss;
    D = (int)p64[0]; H = (int)p64[1]; W = (int)p64[2]; }
  else { D = p32[0]; H = p32[1]; W = p32[2]; }
  int sflag = shifts[0];
  int sx = sflag ? 15 : 0, sy = sflag ? 15 : 0, sz = sflag ? 4 : 0;
  bool wp2 = (W & (W - 1)) == 0, hp2 = (H & (H - 1)) == 0, dp2 = (D & (D - 1)) == 0;
  __syncthreads();

#pragma unroll
  for (int r = 0; r < ROUNDS; ++r) {
    int idx = b * TILE + r * THREADS + t;
    if (idx < N) {
      int4 c = coords[idx];            // (b, z, y, x)
      uint32_t bb = (uint32_t)c.x;
      int zz = c.y + sz, yy = c.z + sy, xx = c.w + sx;
      uint32_t z = (uint32_t)(dp2 ? (zz & (D - 1)) : (zz % D));
      uint32_t y = (uint32_t)(hp2 ? (yy & (H - 1)) : (yy % H));
      uint32_t x = (uint32_t)(wp2 ? (xx & (W - 1)) : (xx % W));
      uint32_t code = hilbert_code(x, y, z) | (bb << 24);
      pairs[idx] = ((uint64_t)(uint32_t)idx << 32) | code;
      atomicAdd(&lh[code & (NBINS - 1)], 1);
    }
  }
  __syncthreads();
  for (int d = t; d < NBINS; d += THREADS) hist[d * nblocks + b] = lh[d];
}

// ---------------- per-pass histogram (keys = low 32 of pair) ----------------
template <int SHIFT>
__global__ __launch_bounds__(THREADS) void hist_kernel(
    const uint64_t* __restrict__ pairs, int* __restrict__ hist, int N, int nblocks) {
  __shared__ int lh[NBINS];
  int t = threadIdx.x, b = blockIdx.x;
  for (int d = t; d < NBINS; d += THREADS) lh[d] = 0;
  __syncthreads();
#pragma unroll
  for (int r = 0; r < ROUNDS; ++r) {
    int idx = b * TILE + r * THREADS + t;
    if (idx < N) atomicAdd(&lh[((uint32_t)pairs[idx] >> SHIFT) & (NBINS - 1)], 1);
  }
  __syncthreads();
  for (int d = t; d < NBINS; d += THREADS) hist[d * nblocks + b] = lh[d];
}

// ---- scan: per digit, exclusive scan over blocks (in place), total out ----
__global__ __launch_bounds__(THREADS) void scan_blocks(
    int* __restrict__ hist, int* __restrict__ digitTotals, int nblocks) {
  __shared__ int s[512];
  int d = blockIdx.x, t = threadIdx.x;
  long long base = (long long)d * nblocks;
  int carry = 0;
  for (int start = 0; start < nblocks; start += 512) {
    int i0 = start + t, i1 = start + t + 256;
    int v0 = (i0 < nblocks) ? hist[base + i0] : 0;
    int v1 = (i1 < nblocks) ? hist[base + i1] : 0;
    s[t] = v0; s[t + 256] = v1;
    __syncthreads();
    for (int off = 1; off < 512; off <<= 1) {
      int a0 = (t >= off) ? s[t - off] : 0;
      int a1 = (t + 256 >= off) ? s[t + 256 - off] : 0;
      int b0 = s[t], b1 = s[t + 256];
      __syncthreads();
      s[t] = b0 + a0; s[t + 256] = b1 + a1;
      __syncthreads();
    }
    if (i0 < nblocks) hist[base + i0] = carry + s[t] - v0;
    if (i1 < nblocks) hist[base + i1] = carry + s[t + 256] - v1;
    int total = s[511];
    __syncthreads();
    carry += total;
  }
  if (t == 0) digitTotals[d] = carry;
}

// ---------------- stable scatter with LDS staging, fused digitBase scan ------
// Stability order within block: (wave, round, lane) == original index order,
// since wave w owns the contiguous chunk [b*TILE + w*CHUNK, +CHUNK).
template <int SHIFT, bool FINAL>
__global__ __launch_bounds__(THREADS) void scatter_kernel(
    const uint64_t* __restrict__ pairsIn,
    uint64_t* __restrict__ pairsOut, int* __restrict__ valsOut,
    const int* __restrict__ hist, const int* __restrict__ digitTotals,
    int N, int nblocks) {
  __shared__ uint64_t sbuf[TILE];                  // staging; reused as int2 scan scratch
  __shared__ unsigned short cnt[4][NBINS];         // per-wave digit counters -> offsets
  __shared__ int adjArr[NBINS];                    // -> digitBase + histExcl - digitStart
  __shared__ int digitStart[NBINS];
  int t = threadIdx.x, b = blockIdx.x;
  int wave = t >> 6, lane = t & 63;

  for (int d = t; d < NBINS; d += THREADS) {
    adjArr[d] = hist[d * nblocks + b];
    cnt[0][d] = 0; cnt[1][d] = 0; cnt[2][d] = 0; cnt[3][d] = 0;
  }
  __syncthreads();

  uint64_t kvR[ROUNDS];
  int drR[ROUNDS];                                 // digit | rankInChunk<<9, -1 invalid
  uint64_t lt = (1ull << lane) - 1ull;
  int chunk0 = b * TILE + wave * CHUNK;

  // ---- phase A: wave-private stable ranking (no barriers) ----
#pragma unroll
  for (int r = 0; r < ROUNDS; ++r) {
    int idx = chunk0 + r * 64 + lane;
    bool valid = idx < N;
    uint64_t kv = valid ? pairsIn[idx] : 0ull;
    kvR[r] = kv;
    int digit = (int)(((uint32_t)kv >> SHIFT) & (NBINS - 1));
    uint64_t eq = __ballot(valid);
#pragma unroll
    for (int bit = 0; bit < RADIX_BITS; ++bit) {
      uint64_t m = __ballot((digit >> bit) & 1);
      eq &= ((digit >> bit) & 1) ? m : ~m;
    }
    int waveRank = __popcll(eq & lt);
    int cntW = __popcll(eq);
    int prior = cnt[wave][digit];                  // wave-private row: no race
    drR[r] = valid ? (digit | ((prior + waveRank) << RADIX_BITS)) : -1;
    if (valid && waveRank == 0) cnt[wave][digit] = (unsigned short)(prior + cntW);
  }
  __syncthreads();

  // ---- cross-wave exclusive offsets; (blockTotal, digitTotal) into scratch --
  int2* s = (int2*)sbuf;
  for (int d = t; d < NBINS; d += THREADS) {
    int c0 = cnt[0][d], c1 = cnt[1][d], c2 = cnt[2][d], c3 = cnt[3][d];
    cnt[0][d] = 0;
    cnt[1][d] = (unsigned short)c0;
    cnt[2][d] = (unsigned short)(c0 + c1);
    cnt[3][d] = (unsigned short)(c0 + c1 + c2);
    s[d] = make_int2(c0 + c1 + c2 + c3, digitTotals[d]);
  }
  __syncthreads();

  // ---- fused 512-wide scan: .x -> digitStart (block), .y -> digitBase -------
  {
    int2 v0 = s[t], v1 = s[t + 256];
    for (int off = 1; off < 512; off <<= 1) {
      int2 a0 = (t >= off) ? s[t - off] : make_int2(0, 0);
      int2 a1 = s[t + 256 - off];
      int2 b0 = s[t], b1 = s[t + 256];
      __syncthreads();
      s[t] = make_int2(b0.x + a0.x, b0.y + a0.y);
      s[t + 256] = make_int2(b1.x + a1.x, b1.y + a1.y);
      __syncthreads();
    }
    int2 i0 = s[t], i1 = s[t + 256];
    int ds0 = i0.x - v0.x, ds1 = i1.x - v1.x;      // exclusive in-block start
    digitStart[t] = ds0;
    digitStart[t + 256] = ds1;
    adjArr[t]       += (i0.y - v0.y) - ds0;        // + digitBase - digitStart
    adjArr[t + 256] += (i1.y - v1.y) - ds1;
  }
  __syncthreads();

  // ---- stage pairs into LDS in digit-sorted order ----
#pragma unroll
  for (int r = 0; r < ROUNDS; ++r) {
    int dr = drR[r];
    if (dr >= 0) {
      int digit = dr & (NBINS - 1);
      int rnk = dr >> RADIX_BITS;
      sbuf[digitStart[digit] + (int)cnt[wave][digit] + rnk] = kvR[r];
    }
  }
  __syncthreads();

  // ---- write out sequentially: runs of a digit are contiguous (avg 64B) ----
  int validCount = min(TILE, N - b * TILE);
#pragma unroll
  for (int j = 0; j < ROUNDS; ++j) {
    int i = j * THREADS + t;
    if (i < validCount) {
      uint64_t kv = sbuf[i];
      int digit = (int)(((uint32_t)kv >> SHIFT) & (NBINS - 1));
      int pos = adjArr[digit] + i;
      if (FINAL) valsOut[pos] = (int)(kv >> 32);
      else pairsOut[pos] = kv;
    }
  }
}

// ---------------- launch ----------------
extern "C" void kernel_launch(void* const* d_in, const int* in_sizes, int n_in,
                              void* d_out, int out_size, void* d_ws, size_t ws_size,
                              hipStream_t stream) {
  const int4* coords = (const int4*)d_in[0];
  const void* ss = d_in[1];
  const int* shifts = (const int*)d_in[2];
  int N = in_sizes[0] / 4;
  int nblocks = (N + TILE - 1) / TILE;

  char* ws = (char*)d_ws;
  size_t off = 0;
  auto alloc = [&](size_t bytes) -> void* {
    void* p = ws + off;
    off += (bytes + 255) & ~(size_t)255;
    return p;
  };
  uint64_t* pairsA = (uint64_t*)alloc((size_t)N * 8);
  uint64_t* pairsB = (uint64_t*)alloc((size_t)N * 8);
  int*      hist   = (int*)alloc((size_t)NBINS * nblocks * 4);
  int*      digitTotals = (int*)alloc(NBINS * 4);

  // pass 0 (bits 0..8): vals implicit (val == idx), fused into genkeys
  genkeys_hist<<<nblocks, THREADS, 0, stream>>>(coords, ss, shifts, pairsA, hist, N, nblocks);
  scan_blocks<<<NBINS, THREADS, 0, stream>>>(hist, digitTotals, nblocks);
  scatter_kernel<0, false><<<nblocks, THREADS, 0, stream>>>(
      pairsA, pairsB, nullptr, hist, digitTotals, N, nblocks);

  // pass 1 (bits 9..17)
  hist_kernel<9><<<nblocks, THREADS, 0, stream>>>(pairsB, hist, N, nblocks);
  scan_blocks<<<NBINS, THREADS, 0, stream>>>(hist, digitTotals, nblocks);
  scatter_kernel<9, false><<<nblocks, THREADS, 0, stream>>>(
      pairsB, pairsA, nullptr, hist, digitTotals, N, nblocks);

  // pass 2 (bits 18..26): vals land directly in d_out
  hist_kernel<18><<<nblocks, THREADS, 0, stream>>>(pairsA, hist, N, nblocks);
  scan_blocks<<<NBINS, THREADS, 0, stream>>>(hist, digitTotals, nblocks);
  scatter_kernel<18, true><<<nblocks, THREADS, 0, stream>>>(
      pairsA, nullptr, (int*)d_out, hist, digitTotals, N, nblocks);
}